// Round 8
// baseline (399.457 us; speedup 1.0000x reference)
//
#include <hip/hip_runtime.h>
#include <hip/hip_cooperative_groups.h>

namespace cg = cooperative_groups;

#define HW    12544   // 112*112
#define HW4   3136    // HW/4
#define NCH   64
#define EPSF  1e-5f

typedef float fvec4 __attribute__((ext_vector_type(4)));

#define RREG  8       // float4s kept in registers per lane (32 VGPRs payload)
#define RLDS  9       // float4s kept in LDS per lane (36 KB/block)
#define RTOT  49      // total float4s per lane (12544 / 4 / 64)

// -------- fused persistent cooperative kernel --------
// 1024 blocks x 256 threads = 4096 waves, one plane per wave.
// Per lane: 49 fvec4. 8 in VGPRs, 9 in LDS, 32 re-read in phase 2.
// ws: [0,4096) s_part[p], [4096,8192) ss_part[p].

__global__ __launch_bounds__(256, 4) void cn_fused(
    const float* __restrict__ x, const int* __restrict__ labels,
    const float* __restrict__ rmean, const float* __restrict__ rvar,
    const float* __restrict__ wgt, const float* __restrict__ bia,
    float* __restrict__ ws, float* __restrict__ out)
{
    __shared__ fvec4 lds4[4 * RLDS * 64];   // 36864 B/block -> 4 blocks/CU = 144 KB

    const int l = threadIdx.x & 63;
    const int w = threadIdx.x >> 6;
    const int p = blockIdx.x * 4 + w;       // plane = b*64 + c
    const int b = p >> 6;
    const int c = p & 63;

    const fvec4* xp = (const fvec4*)(x + (size_t)p * HW);
    fvec4* lw = lds4 + w * (RLDS * 64);

    // ---- phase 1: load + per-plane partial sums ----
    fvec4 r[RREG];
    float s = 0.0f, ss = 0.0f;
    #pragma unroll
    for (int k = 0; k < RREG; ++k) {
        fvec4 v = xp[k * 64 + l];
        r[k] = v;
        s  += v.x + v.y + v.z + v.w;
        ss += v.x * v.x + v.y * v.y + v.z * v.z + v.w * v.w;
    }
    #pragma unroll
    for (int k = RREG; k < RREG + RLDS; ++k) {
        fvec4 v = xp[k * 64 + l];
        lw[(k - RREG) * 64 + l] = v;
        s  += v.x + v.y + v.z + v.w;
        ss += v.x * v.x + v.y * v.y + v.z * v.z + v.w * v.w;
    }
    #pragma unroll
    for (int k = RREG + RLDS; k < RTOT; ++k) {
        fvec4 v = xp[k * 64 + l];
        s  += v.x + v.y + v.z + v.w;
        ss += v.x * v.x + v.y * v.y + v.z * v.z + v.w * v.w;
    }
    #pragma unroll
    for (int off = 32; off > 0; off >>= 1) {
        s  += __shfl_xor(s,  off, 64);
        ss += __shfl_xor(ss, off, 64);
    }
    if (l == 0) { ws[p] = s; ws[4096 + p] = ss; }

    __threadfence();
    cg::this_grid().sync();

    // ---- phase 2: cluster stats (all lanes end with scale/shift) ----
    int g  = labels[b];
    int lb = labels[l];
    bool m = (lb == g);
    float s2  = m ? ws[l * NCH + c]        : 0.0f;
    float ss2 = m ? ws[4096 + l * NCH + c] : 0.0f;
    float cnt = m ? 1.0f : 0.0f;
    #pragma unroll
    for (int off = 32; off > 0; off >>= 1) {
        s2  += __shfl_xor(s2,  off, 64);
        ss2 += __shfl_xor(ss2, off, 64);
        cnt += __shfl_xor(cnt, off, 64);
    }
    float N    = cnt * (float)HW;
    float mean = s2 / fmaxf(N, 1.0f);
    float var  = (ss2 - N * mean * mean) / fmaxf(N - 1.0f, 1.0f);
    float mu   = 0.2f * mean + 0.8f * rmean[c];
    float vb   = 0.2f * var  + 0.8f * rvar[c];
    float scale = rsqrtf(vb + EPSF) * wgt[c];
    float shift = bia[c] - mu * scale;

    // ---- normalize: regs, then LDS, then re-read tail ----
    fvec4* op = (fvec4*)(out + (size_t)p * HW);
    #pragma unroll
    for (int k = 0; k < RREG; ++k) {
        fvec4 o = r[k] * scale + shift;
        __builtin_nontemporal_store(o, &op[k * 64 + l]);
    }
    #pragma unroll
    for (int k = RREG; k < RREG + RLDS; ++k) {
        fvec4 v = lw[(k - RREG) * 64 + l];
        fvec4 o = v * scale + shift;
        __builtin_nontemporal_store(o, &op[k * 64 + l]);
    }
    #pragma unroll
    for (int k = RREG + RLDS; k < RTOT; ++k) {
        fvec4 v = xp[k * 64 + l];
        fvec4 o = v * scale + shift;
        __builtin_nontemporal_store(o, &op[k * 64 + l]);
    }
}

// -------- fallback: proven round-3 two-kernel path --------

__global__ __launch_bounds__(256) void cn_stats(const float* __restrict__ x,
                                                float* __restrict__ ws) {
    int p = blockIdx.x;
    const fvec4* xp = (const fvec4*)(x + (size_t)p * HW);
    float s = 0.0f, ss = 0.0f;
    for (int i = threadIdx.x; i < HW4; i += 256) {
        fvec4 v = xp[i];
        s  += v.x + v.y + v.z + v.w;
        ss += v.x * v.x + v.y * v.y + v.z * v.z + v.w * v.w;
    }
    #pragma unroll
    for (int off = 32; off > 0; off >>= 1) {
        s  += __shfl_down(s, off, 64);
        ss += __shfl_down(ss, off, 64);
    }
    __shared__ float sh[8];
    int lane = threadIdx.x & 63;
    int wave = threadIdx.x >> 6;
    if (lane == 0) { sh[wave] = s; sh[4 + wave] = ss; }
    __syncthreads();
    if (threadIdx.x == 0) {
        ws[p]        = sh[0] + sh[1] + sh[2] + sh[3];
        ws[4096 + p] = sh[4] + sh[5] + sh[6] + sh[7];
    }
}

__global__ __launch_bounds__(256) void cn_norm(const float* __restrict__ x,
                                               const int* __restrict__ labels,
                                               const float* __restrict__ rmean,
                                               const float* __restrict__ rvar,
                                               const float* __restrict__ wgt,
                                               const float* __restrict__ bia,
                                               const float* __restrict__ ws,
                                               float* __restrict__ out) {
    int p = blockIdx.x;
    int b = p >> 6;
    int c = p & 63;
    __shared__ float sh_scale, sh_shift;
    if (threadIdx.x < 64) {
        int t  = threadIdx.x;
        int g  = labels[b];
        int lb = labels[t];
        bool m = (lb == g);
        float s   = m ? ws[t * NCH + c]        : 0.0f;
        float ss  = m ? ws[4096 + t * NCH + c] : 0.0f;
        float cnt = m ? 1.0f : 0.0f;
        #pragma unroll
        for (int off = 32; off > 0; off >>= 1) {
            s   += __shfl_down(s,   off, 64);
            ss  += __shfl_down(ss,  off, 64);
            cnt += __shfl_down(cnt, off, 64);
        }
        if (t == 0) {
            float N    = cnt * (float)HW;
            float mean = s / fmaxf(N, 1.0f);
            float var  = (ss - N * mean * mean) / fmaxf(N - 1.0f, 1.0f);
            float mu   = 0.2f * mean + 0.8f * rmean[c];
            float vb   = 0.2f * var  + 0.8f * rvar[c];
            float scale = rsqrtf(vb + EPSF) * wgt[c];
            sh_scale = scale;
            sh_shift = bia[c] - mu * scale;
        }
    }
    __syncthreads();
    float scale = sh_scale;
    float shift = sh_shift;
    const fvec4* xp = (const fvec4*)(x + (size_t)p * HW);
    fvec4*       op = (fvec4*)(out + (size_t)p * HW);
    for (int i = threadIdx.x; i < HW4; i += 256) {
        fvec4 v = xp[i];
        fvec4 o;
        o.x = v.x * scale + shift;
        o.y = v.y * scale + shift;
        o.z = v.z * scale + shift;
        o.w = v.w * scale + shift;
        __builtin_nontemporal_store(o, &op[i]);
    }
}

extern "C" void kernel_launch(void* const* d_in, const int* in_sizes, int n_in,
                              void* d_out, int out_size, void* d_ws, size_t ws_size,
                              hipStream_t stream) {
    const float* x      = (const float*)d_in[0];
    const float* rmean  = (const float*)d_in[1];
    const float* rvar   = (const float*)d_in[2];
    const float* wgt    = (const float*)d_in[3];
    const float* bia    = (const float*)d_in[4];
    const int*   labels = (const int*)d_in[5];
    float* out = (float*)d_out;
    float* ws  = (float*)d_ws;

    void* args[] = {(void*)&x, (void*)&labels, (void*)&rmean, (void*)&rvar,
                    (void*)&wgt, (void*)&bia, (void*)&ws, (void*)&out};
    hipError_t err = hipLaunchCooperativeKernel((const void*)cn_fused, dim3(1024),
                                                dim3(256), args, 0, stream);
    if (err != hipSuccess) {
        // deterministic fallback: proven 2-kernel path (~97 us)
        const int planes = 64 * NCH; // 4096
        cn_stats<<<planes, 256, 0, stream>>>(x, ws);
        cn_norm <<<planes, 256, 0, stream>>>(x, labels, rmean, rvar, wgt, bia, ws, out);
    }
}

// Round 9
// 96.978 us; speedup vs baseline: 4.1190x; 4.1190x over previous
//
#include <hip/hip_runtime.h>

#define HW    12544   // 112*112
#define HW4   3136    // HW/4
#define NCH   64      // channels
#define NB    64      // batch
#define EPSF  1e-5f

typedef float fvec4 __attribute__((ext_vector_type(4)));

// ws layout (floats): [0,4096)     s_part[b*64+c]
//                     [4096,8192)  ss_part[b*64+c]
// (fully overwritten by cn_stats every call -> no zeroing, no atomics)
//
// Structure (proven round-3): two streaming dispatches at full occupancy.
// Traffic = read x (205.5 MB) + re-read x (205.5) + write out (205.5) = 616 MB
// ~= the structural floor; on-chip holding of x was tried (cooperative kernel,
// R7/R8) and is MLP-fatal: it runs at 1.3 TB/s vs 6.4 TB/s for this version.

__global__ __launch_bounds__(256) void cn_stats(const float* __restrict__ x,
                                                float* __restrict__ ws) {
    int p = blockIdx.x;            // plane index = b*NCH + c
    const fvec4* xp = (const fvec4*)(x + (size_t)p * HW);
    float s = 0.0f, ss = 0.0f;
    for (int i = threadIdx.x; i < HW4; i += 256) {
        fvec4 v = xp[i];
        s  += v.x + v.y + v.z + v.w;
        ss += v.x * v.x + v.y * v.y + v.z * v.z + v.w * v.w;
    }
    #pragma unroll
    for (int off = 32; off > 0; off >>= 1) {
        s  += __shfl_down(s, off, 64);
        ss += __shfl_down(ss, off, 64);
    }
    __shared__ float sh[8];
    int lane = threadIdx.x & 63;
    int wave = threadIdx.x >> 6;
    if (lane == 0) { sh[wave] = s; sh[4 + wave] = ss; }
    __syncthreads();
    if (threadIdx.x == 0) {
        ws[p]        = sh[0] + sh[1] + sh[2] + sh[3];
        ws[4096 + p] = sh[4] + sh[5] + sh[6] + sh[7];
    }
}

__global__ __launch_bounds__(256) void cn_norm(const float* __restrict__ x,
                                               const int* __restrict__ labels,
                                               const float* __restrict__ rmean,
                                               const float* __restrict__ rvar,
                                               const float* __restrict__ wgt,
                                               const float* __restrict__ bia,
                                               const float* __restrict__ ws,
                                               float* __restrict__ out) {
    int p = blockIdx.x;
    int b = p >> 6;
    int c = p & 63;
    __shared__ float sh_scale, sh_shift;
    if (threadIdx.x < 64) {
        int t  = threadIdx.x;
        int g  = labels[b];         // this sample's cluster
        int lb = labels[t];         // lane t inspects sample t
        bool m = (lb == g);
        float s   = m ? ws[t * NCH + c]        : 0.0f;
        float ss  = m ? ws[4096 + t * NCH + c] : 0.0f;
        float cnt = m ? 1.0f : 0.0f;
        #pragma unroll
        for (int off = 32; off > 0; off >>= 1) {
            s   += __shfl_down(s,   off, 64);
            ss  += __shfl_down(ss,  off, 64);
            cnt += __shfl_down(cnt, off, 64);
        }
        if (t == 0) {
            float N    = cnt * (float)HW;
            float mean = s / fmaxf(N, 1.0f);
            float var  = (ss - N * mean * mean) / fmaxf(N - 1.0f, 1.0f);
            float mu   = 0.2f * mean + 0.8f * rmean[c];
            float vb   = 0.2f * var  + 0.8f * rvar[c];
            float scale = rsqrtf(vb + EPSF) * wgt[c];
            sh_scale = scale;
            sh_shift = bia[c] - mu * scale;
        }
    }
    __syncthreads();
    float scale = sh_scale;
    float shift = sh_shift;
    const fvec4* xp = (const fvec4*)(x + (size_t)p * HW);
    fvec4*       op = (fvec4*)(out + (size_t)p * HW);
    for (int i = threadIdx.x; i < HW4; i += 256) {
        fvec4 v = xp[i];
        fvec4 o;
        o.x = v.x * scale + shift;
        o.y = v.y * scale + shift;
        o.z = v.z * scale + shift;
        o.w = v.w * scale + shift;
        __builtin_nontemporal_store(o, &op[i]);
    }
}

extern "C" void kernel_launch(void* const* d_in, const int* in_sizes, int n_in,
                              void* d_out, int out_size, void* d_ws, size_t ws_size,
                              hipStream_t stream) {
    const float* x      = (const float*)d_in[0];
    const float* rmean  = (const float*)d_in[1];
    const float* rvar   = (const float*)d_in[2];
    const float* wgt    = (const float*)d_in[3];
    const float* bia    = (const float*)d_in[4];
    const int*   labels = (const int*)d_in[5];
    float* out = (float*)d_out;
    float* ws  = (float*)d_ws;

    const int planes = NB * NCH; // 4096

    cn_stats<<<planes, 256, 0, stream>>>(x, ws);
    cn_norm<<<planes, 256, 0, stream>>>(x, labels, rmean, rvar, wgt, bia, ws, out);
}